// Round 10
// baseline (34.495 us; speedup 1.0000x reference)
//
#include <hip/hip_runtime.h>
#include <hip/hip_bf16.h>

// out[b,n,:] = relu([v_bn, emb[n]] @ W1 + b1) @ W2 + b2,  v_bn = abs_actions[b, asgn[b,n]]
// Split: base[n,h] = emb[n]@W1[1:,h] + b1[h]  (bf16 MFMA, r4-verified)
//        out[b,n,o] = sum_h relu(base[n,h] + v*w1r[h]) * W2[h,o] + b2[o]
//                     (r6-verified MFMA phase 2; store via LDS stage + coalesced pass)
// Round 10: prep 16->64 blocks; phase-2 MFMA with fixed (coalesced) stores.

constexpr int B_ = 32, A_ = 16, N_ = 10000, E_ = 256, H_ = 256;
constexpr int TN = 16, NBLK = N_ / TN;   // 625 blocks

typedef __attribute__((ext_vector_type(8))) short bf16x8;
typedef __attribute__((ext_vector_type(4))) float f32x4;

__device__ __align__(16) ushort g_w1t[H_ * E_];   // [h][k] bf16 of W1[1+k][h]

static __device__ __forceinline__ ushort f2bf(float x) {
    union { float f; unsigned u; } c; c.f = x;
    unsigned r = c.u + 0x7fff + ((c.u >> 16) & 1);   // RNE
    return (ushort)(r >> 16);
}

static __device__ __forceinline__ ushort2 pk2(float lo, float hi) {
    union { __hip_bfloat162 h; ushort2 u; } c;
    c.h = __float22bfloat162_rn(float2{lo, hi});     // hw cvt_pk, RNE
    return c.u;
}

// 64 blocks, 32x32 tiles: 4x the parallelism of the old 16-block version
__global__ __launch_bounds__(256, 1) void prep_w1t_k(const float* __restrict__ W1) {
    __shared__ float tile[32][33];
    const int bk = blockIdx.x >> 3, bh = blockIdx.x & 7;
    const int tx = threadIdx.x & 31, ty = threadIdx.x >> 5;
    #pragma unroll
    for (int kk = ty; kk < 32; kk += 8)
        tile[kk][tx] = W1[(size_t)(1 + bk * 32 + kk) * H_ + bh * 32 + tx];
    __syncthreads();
    #pragma unroll
    for (int hh = ty; hh < 32; hh += 8)
        g_w1t[(size_t)(bh * 32 + hh) * E_ + bk * 32 + tx] = f2bf(tile[tx][hh]);
}

__global__ __launch_bounds__(256, 4) void decoder_main(
    const float* __restrict__ abs_actions,  // (32,16)
    const int*   __restrict__ asgn,         // (32,10000)
    const float* __restrict__ emb,          // (10000,256)
    const float* __restrict__ W1,           // (257,256)
    const float* __restrict__ b1,           // (256)
    const float* __restrict__ W2,           // (256,2)
    const float* __restrict__ b2,           // (2)
    float* __restrict__ out)                // (32,10000,2)
{
    __shared__ ushort eb[TN * 264];     // emb tile bf16, pitch 264
    __shared__ float  u[TN * 260];      // base tile f32, pitch 260
    __shared__ float  vals[B_ * 17];    // v[b][n], pitch 17
    __shared__ float  w1r[H_];          // W1 row 0
    __shared__ float  w2s[2 * H_];      // W2 flat [h*2+o]
    __shared__ float  po[2 * 544];      // D stage: [o][b*17+n]

    const int t  = threadIdx.x;
    const int n0 = blockIdx.x * TN;

    // ---- stage vals (r4-verified)
    #pragma unroll
    for (int q = 0; q < 2; ++q) {
        const int p = t + 256 * q, b = p >> 4, n = p & 15;
        vals[b * 17 + n] = abs_actions[b * A_ + asgn[(size_t)b * N_ + n0 + n]];
    }

    // ---- stage emb tile -> bf16 LDS (r4-verified)
    {
        const int row = t >> 4, col = (t & 15) << 4;
        const float4* src = reinterpret_cast<const float4*>(emb + (size_t)(n0 + row) * E_ + col);
        const float4 q0 = src[0], q1 = src[1], q2 = src[2], q3 = src[3];
        union { ushort us[16]; bf16x8 v[2]; } pk;
        const float f[16] = {q0.x,q0.y,q0.z,q0.w, q1.x,q1.y,q1.z,q1.w,
                             q2.x,q2.y,q2.z,q2.w, q3.x,q3.y,q3.z,q3.w};
        #pragma unroll
        for (int i = 0; i < 16; ++i) pk.us[i] = f2bf(f[i]);
        bf16x8* dst = reinterpret_cast<bf16x8*>(&eb[row * 264 + col]);
        dst[0] = pk.v[0]; dst[1] = pk.v[1];
    }
    w1r[t]       = W1[t];
    w2s[t]       = W2[t];
    w2s[256 + t] = W2[256 + t];
    __syncthreads();

    // ---- phase 1: base = emb @ W1[1:] + b1 (MFMA 16x16x32 bf16; r4-verified)
    {
        const int lane = t & 63, w = t >> 6;
        const int lr = lane & 15;
        const int lk = (lane >> 4) << 3;
        f32x4 acc[4];
        #pragma unroll
        for (int ct = 0; ct < 4; ++ct) {
            const float bv = b1[w * 64 + ct * 16 + lr];
            acc[ct] = (f32x4){bv, bv, bv, bv};
        }
        #pragma unroll
        for (int ks = 0; ks < 8; ++ks) {
            const bf16x8 af = *reinterpret_cast<const bf16x8*>(&eb[lr * 264 + ks * 32 + lk]);
            #pragma unroll
            for (int ct = 0; ct < 4; ++ct) {
                const bf16x8 bfv = *reinterpret_cast<const bf16x8*>(
                    &g_w1t[(size_t)(w * 64 + ct * 16 + lr) * E_ + ks * 32 + lk]);
                acc[ct] = __builtin_amdgcn_mfma_f32_16x16x32_bf16(af, bfv, acc[ct], 0, 0, 0);
            }
        }
        // D: col = lane&15, row = (lane>>4)*4 + r   [r4-verified]
        #pragma unroll
        for (int ct = 0; ct < 4; ++ct)
            #pragma unroll
            for (int r = 0; r < 4; ++r)
                u[((lane >> 4) * 4 + r) * 260 + w * 64 + ct * 16 + lr] = acc[ct][r];
    }
    __syncthreads();

    // ---- phase 2: out = P @ W2 via MFMA (r6-verified maps). Wave w owns n = 4w..4w+3.
    // A-frag: lane supplies P[b = lane&15][k = (lane>>4)*8 + j]
    // B-frag: lane holds W2bf[k][col = lane&15], cols >= 2 zero
    // D:      lane holds D[b = (lane>>4)*4 + r][o = lane&15]
    {
        const int lane = t & 63, w = t >> 6;
        const int lr  = lane & 15;      // A-row (b within half) AND D-col (o)
        const int klo = lane >> 4;      // k sub-slice; D row group
        const int wn0 = w * 4;          // this wave's n rows

        bf16x8 w2f[8];
        #pragma unroll
        for (int ks = 0; ks < 8; ++ks) {
            union { ushort us[8]; bf16x8 v; } pk;
            #pragma unroll
            for (int j = 0; j < 8; ++j) {
                const int h = ks * 32 + klo * 8 + j;
                pk.us[j] = (lr < 2) ? f2bf(w2s[h * 2 + lr]) : (ushort)0;
            }
            w2f[ks] = pk.v;
        }

        float vv[4][2];
        #pragma unroll
        for (int n = 0; n < 4; ++n)
            #pragma unroll
            for (int bh = 0; bh < 2; ++bh)
                vv[n][bh] = vals[(bh * 16 + lr) * 17 + wn0 + n];

        f32x4 acc[4][2] = {};           // [n][bhalf]

        #pragma unroll
        for (int ks = 0; ks < 8; ++ks) {
            const int k0 = ks * 32 + klo * 8;
            const float4 wv0 = *reinterpret_cast<const float4*>(&w1r[k0]);
            const float4 wv1 = *reinterpret_cast<const float4*>(&w1r[k0 + 4]);
            #pragma unroll
            for (int n = 0; n < 4; ++n) {
                const float4 u0 = *reinterpret_cast<const float4*>(&u[(wn0 + n) * 260 + k0]);
                const float4 u1 = *reinterpret_cast<const float4*>(&u[(wn0 + n) * 260 + k0 + 4]);
                #pragma unroll
                for (int bh = 0; bh < 2; ++bh) {
                    const float v = vv[n][bh];
                    const float p0 = fmaxf(fmaf(v, wv0.x, u0.x), 0.f);
                    const float p1 = fmaxf(fmaf(v, wv0.y, u0.y), 0.f);
                    const float p2 = fmaxf(fmaf(v, wv0.z, u0.z), 0.f);
                    const float p3 = fmaxf(fmaf(v, wv0.w, u0.w), 0.f);
                    const float p4 = fmaxf(fmaf(v, wv1.x, u1.x), 0.f);
                    const float p5 = fmaxf(fmaf(v, wv1.y, u1.y), 0.f);
                    const float p6 = fmaxf(fmaf(v, wv1.z, u1.z), 0.f);
                    const float p7 = fmaxf(fmaf(v, wv1.w, u1.w), 0.f);
                    union { ushort2 u2[4]; bf16x8 v8; } pa;
                    pa.u2[0] = pk2(p0, p1);
                    pa.u2[1] = pk2(p2, p3);
                    pa.u2[2] = pk2(p4, p5);
                    pa.u2[3] = pk2(p6, p7);
                    acc[n][bh] = __builtin_amdgcn_mfma_f32_16x16x32_bf16(
                        pa.v8, w2f[ks], acc[n][bh], 0, 0, 0);
                }
            }
        }

        // stage D to LDS: po[o][b*17 + n]  (complete sums; pure data movement)
        if (lr < 2) {
            #pragma unroll
            for (int n = 0; n < 4; ++n)
                #pragma unroll
                for (int bh = 0; bh < 2; ++bh)
                    #pragma unroll
                    for (int r = 0; r < 4; ++r) {
                        const int b = bh * 16 + klo * 4 + r;
                        po[lr * 544 + b * 17 + (wn0 + n)] = acc[n][bh][r];
                    }
        }
    }
    __syncthreads();

    // ---- final: coalesced float2 stores, 2 (b,n) pairs per thread
    {
        const float b20 = b2[0], b21 = b2[1];
        #pragma unroll
        for (int q = 0; q < 2; ++q) {
            const int p = t + 256 * q, b = p >> 4, n = p & 15;
            float2 o;
            o.x = po[b * 17 + n] + b20;
            o.y = po[544 + b * 17 + n] + b21;
            *reinterpret_cast<float2*>(out + ((size_t)b * N_ + n0 + n) * 2) = o;
        }
    }
}

extern "C" void kernel_launch(void* const* d_in, const int* in_sizes, int n_in,
                              void* d_out, int out_size, void* d_ws, size_t ws_size,
                              hipStream_t stream) {
    const float* abs_actions = (const float*)d_in[0];
    const int*   asgn        = (const int*)d_in[1];
    const float* emb         = (const float*)d_in[2];
    const float* W1          = (const float*)d_in[3];
    const float* b1          = (const float*)d_in[4];
    const float* W2          = (const float*)d_in[5];
    const float* b2          = (const float*)d_in[6];
    float*       out         = (float*)d_out;

    prep_w1t_k<<<64, 256, 0, stream>>>(W1);
    decoder_main<<<NBLK, 256, 0, stream>>>(abs_actions, asgn, emb, W1, b1, W2, b2, out);
}

// Round 11
// 30.154 us; speedup vs baseline: 1.1440x; 1.1440x over previous
//
#include <hip/hip_runtime.h>

// out[b,n,:] = relu([v_bn, emb[n]] @ W1 + b1) @ W2 + b2,  v_bn = abs_actions[b, asgn[b,n]]
// Split: base[n,h] = emb[n]@W1[1:,h] + b1[h]  (bf16 MFMA, r4-verified)
//        out[b,n]  = relu(base[n,:] + v*W1[0,:]) @ W2 + b2  (fp32 VALU, r9-verified)
// Round 11: r9 main (best, 30.0us) + r10's 64-block prep (4x transpose parallelism).

constexpr int B_ = 32, A_ = 16, N_ = 10000, E_ = 256, H_ = 256;
constexpr int TN = 16, NBLK = N_ / TN;   // 625 blocks, 10000 exactly

typedef __attribute__((ext_vector_type(8))) short bf16x8;
typedef __attribute__((ext_vector_type(4))) float f32x4;

__device__ __align__(16) ushort g_w1t[H_ * E_];   // [h][k] bf16 of W1[1+k][h]

static __device__ __forceinline__ ushort f2bf(float x) {
    union { float f; unsigned u; } c; c.f = x;
    unsigned r = c.u + 0x7fff + ((c.u >> 16) & 1);   // RNE
    return (ushort)(r >> 16);
}

// 64 blocks, 32x32 tiles (r10-verified)
__global__ __launch_bounds__(256, 1) void prep_w1t_k(const float* __restrict__ W1) {
    __shared__ float tile[32][33];
    const int bk = blockIdx.x >> 3, bh = blockIdx.x & 7;
    const int tx = threadIdx.x & 31, ty = threadIdx.x >> 5;
    #pragma unroll
    for (int kk = ty; kk < 32; kk += 8)
        tile[kk][tx] = W1[(size_t)(1 + bk * 32 + kk) * H_ + bh * 32 + tx];
    __syncthreads();
    #pragma unroll
    for (int hh = ty; hh < 32; hh += 8)
        g_w1t[(size_t)(bh * 32 + hh) * E_ + bk * 32 + tx] = f2bf(tile[tx][hh]);
}

__global__ __launch_bounds__(256, 4) void decoder_main(
    const float* __restrict__ abs_actions,  // (32,16)
    const int*   __restrict__ asgn,         // (32,10000)
    const float* __restrict__ emb,          // (10000,256)
    const float* __restrict__ W1,           // (257,256)
    const float* __restrict__ b1,           // (256)
    const float* __restrict__ W2,           // (256,2)
    const float* __restrict__ b2,           // (2)
    float* __restrict__ out)                // (32,10000,2)
{
    __shared__ ushort eb[TN * 264];     // emb tile bf16, pitch 264
    __shared__ float  u[TN * 260];      // base tile f32, pitch 260
    __shared__ float  vals[B_ * 17];    // v[b][n], pitch 17
    __shared__ float  w1r[H_];          // W1 row 0
    __shared__ float  w2s[2 * H_];      // W2 flat [h*2+o]

    const int t  = threadIdx.x;
    const int n0 = blockIdx.x * TN;

    // ---- stage vals (r4-verified)
    #pragma unroll
    for (int q = 0; q < 2; ++q) {
        const int p = t + 256 * q, b = p >> 4, n = p & 15;
        vals[b * 17 + n] = abs_actions[b * A_ + asgn[(size_t)b * N_ + n0 + n]];
    }

    // ---- stage emb tile -> bf16 LDS (r4-verified)
    {
        const int row = t >> 4, col = (t & 15) << 4;
        const float4* src = reinterpret_cast<const float4*>(emb + (size_t)(n0 + row) * E_ + col);
        const float4 q0 = src[0], q1 = src[1], q2 = src[2], q3 = src[3];
        union { ushort us[16]; bf16x8 v[2]; } pk;
        const float f[16] = {q0.x,q0.y,q0.z,q0.w, q1.x,q1.y,q1.z,q1.w,
                             q2.x,q2.y,q2.z,q2.w, q3.x,q3.y,q3.z,q3.w};
        #pragma unroll
        for (int i = 0; i < 16; ++i) pk.us[i] = f2bf(f[i]);
        bf16x8* dst = reinterpret_cast<bf16x8*>(&eb[row * 264 + col]);
        dst[0] = pk.v[0]; dst[1] = pk.v[1];
    }
    w1r[t]       = W1[t];
    w2s[t]       = W2[t];
    w2s[256 + t] = W2[256 + t];
    __syncthreads();

    // ---- phase 1: base = emb @ W1[1:] + b1 (MFMA 16x16x32 bf16; r4-verified)
    {
        const int lane = t & 63, w = t >> 6;
        const int lr = lane & 15;
        const int lk = (lane >> 4) << 3;
        f32x4 acc[4];
        #pragma unroll
        for (int ct = 0; ct < 4; ++ct) {
            const float bv = b1[w * 64 + ct * 16 + lr];
            acc[ct] = (f32x4){bv, bv, bv, bv};
        }
        #pragma unroll
        for (int ks = 0; ks < 8; ++ks) {
            const bf16x8 af = *reinterpret_cast<const bf16x8*>(&eb[lr * 264 + ks * 32 + lk]);
            #pragma unroll
            for (int ct = 0; ct < 4; ++ct) {
                const bf16x8 bfv = *reinterpret_cast<const bf16x8*>(
                    &g_w1t[(size_t)(w * 64 + ct * 16 + lr) * E_ + ks * 32 + lk]);
                acc[ct] = __builtin_amdgcn_mfma_f32_16x16x32_bf16(af, bfv, acc[ct], 0, 0, 0);
            }
        }
        // D: col = lane&15, row = (lane>>4)*4 + r   [r4-verified]
        #pragma unroll
        for (int ct = 0; ct < 4; ++ct)
            #pragma unroll
            for (int r = 0; r < 4; ++r)
                u[((lane >> 4) * 4 + r) * 260 + w * 64 + ct * 16 + lr] = acc[ct][r];
    }
    __syncthreads();

    // ---- phase 2: thread = (bg = t>>4, n = t&15), 2 b's each, FULL-h loop (r9-verified)
    {
        const int bg = t >> 4, n = t & 15;
        const float b20 = b2[0], b21 = b2[1];
        const float v0 = vals[(bg * 2 + 0) * 17 + n];
        const float v1 = vals[(bg * 2 + 1) * 17 + n];
        float o00 = 0.f, o01 = 0.f, o10 = 0.f, o11 = 0.f;

        const float* br = &u[n * 260];
        #pragma unroll 4
        for (int h = 0; h < 256; h += 4) {
            const float4 c  = *reinterpret_cast<const float4*>(&br[h]);
            const float4 wv = *reinterpret_cast<const float4*>(&w1r[h]);
            const float4 p0 = *reinterpret_cast<const float4*>(&w2s[2 * h]);
            const float4 p1 = *reinterpret_cast<const float4*>(&w2s[2 * h + 4]);
            // b = bg*2
            {
                const float r0 = fmaxf(fmaf(v0, wv.x, c.x), 0.f);
                const float r1 = fmaxf(fmaf(v0, wv.y, c.y), 0.f);
                const float r2 = fmaxf(fmaf(v0, wv.z, c.z), 0.f);
                const float r3 = fmaxf(fmaf(v0, wv.w, c.w), 0.f);
                o00 = fmaf(r0, p0.x, o00);
                o01 = fmaf(r0, p0.y, o01);
                o00 = fmaf(r1, p0.z, o00);
                o01 = fmaf(r1, p0.w, o01);
                o00 = fmaf(r2, p1.x, o00);
                o01 = fmaf(r2, p1.y, o01);
                o00 = fmaf(r3, p1.z, o00);
                o01 = fmaf(r3, p1.w, o01);
            }
            // b = bg*2 + 1
            {
                const float r0 = fmaxf(fmaf(v1, wv.x, c.x), 0.f);
                const float r1 = fmaxf(fmaf(v1, wv.y, c.y), 0.f);
                const float r2 = fmaxf(fmaf(v1, wv.z, c.z), 0.f);
                const float r3 = fmaxf(fmaf(v1, wv.w, c.w), 0.f);
                o10 = fmaf(r0, p0.x, o10);
                o11 = fmaf(r0, p0.y, o11);
                o10 = fmaf(r1, p0.z, o10);
                o11 = fmaf(r1, p0.w, o11);
                o10 = fmaf(r2, p1.x, o10);
                o11 = fmaf(r2, p1.y, o11);
                o10 = fmaf(r3, p1.z, o10);
                o11 = fmaf(r3, p1.w, o11);
            }
        }

        float2 oa; oa.x = o00 + b20; oa.y = o01 + b21;
        float2 ob; ob.x = o10 + b20; ob.y = o11 + b21;
        *reinterpret_cast<float2*>(out + ((size_t)(bg * 2 + 0) * N_ + n0 + n) * 2) = oa;
        *reinterpret_cast<float2*>(out + ((size_t)(bg * 2 + 1) * N_ + n0 + n) * 2) = ob;
    }
}

extern "C" void kernel_launch(void* const* d_in, const int* in_sizes, int n_in,
                              void* d_out, int out_size, void* d_ws, size_t ws_size,
                              hipStream_t stream) {
    const float* abs_actions = (const float*)d_in[0];
    const int*   asgn        = (const int*)d_in[1];
    const float* emb         = (const float*)d_in[2];
    const float* W1          = (const float*)d_in[3];
    const float* b1          = (const float*)d_in[4];
    const float* W2          = (const float*)d_in[5];
    const float* b2          = (const float*)d_in[6];
    float*       out         = (float*)d_out;

    prep_w1t_k<<<64, 256, 0, stream>>>(W1);
    decoder_main<<<NBLK, 256, 0, stream>>>(abs_actions, asgn, emb, W1, b1, W2, b2, out);
}